// Round 1
// baseline (848.675 us; speedup 1.0000x reference)
//
#include <hip/hip_runtime.h>

// Problem constants
#define BB   4
#define NN   16384
#define KK   32
#define INF  32
#define PEF  64
#define HID  128
#define OUTF 64

// ---------------------------------------------------------------------------
// Prep kernel: Wc = pe_w2 @ W1b  (64 x 128), b1c = mlp_b1 + pe_b2 @ W1b
// W1b = rows 32..95 of mlp_w1 (96 x 128, row-major).
// One block of 256 threads: thread t -> column j = t & 127, half = t >> 7
// handles rows i in [half*32, half*32+32).
// ---------------------------------------------------------------------------
__global__ __launch_bounds__(256) void prep_kernel(
    const float* __restrict__ pe_w2,   // (64,64)
    const float* __restrict__ pe_b2,   // (64)
    const float* __restrict__ mlp_w1,  // (96,128)
    const float* __restrict__ mlp_b1,  // (128)
    float* __restrict__ wc,            // (64,128) out
    float* __restrict__ b1c)           // (128) out
{
    __shared__ float s_w2[64 * 64];
    __shared__ float s_b2[64];
    int t = threadIdx.x;
    for (int i = t; i < 64 * 64; i += 256) s_w2[i] = pe_w2[i];
    if (t < 64) s_b2[t] = pe_b2[t];
    __syncthreads();

    int j    = t & 127;
    int half = t >> 7;

    // Column j of W1b into registers
    float col[64];
#pragma unroll
    for (int c = 0; c < 64; ++c) col[c] = mlp_w1[(32 + c) * HID + j];

    if (half == 0) {
        float bacc = mlp_b1[j];
#pragma unroll 16
        for (int c = 0; c < 64; ++c) bacc = fmaf(s_b2[c], col[c], bacc);
        b1c[j] = bacc;
    }

    for (int i = half * 32; i < half * 32 + 32; ++i) {
        float a = 0.f;
#pragma unroll 16
        for (int c = 0; c < 64; ++c) a = fmaf(s_w2[i * 64 + c], col[c], a);
        wc[i * HID + j] = a;
    }
}

// ---------------------------------------------------------------------------
// Main kernel: one wave per point. 256 threads = 4 waves = 4 points per block.
// Lane l computes hidden columns j0 = l and j1 = l + 64.
// out[m, :] = (mean_k relu(nb_feat@W1a + peh@Wc + b1c)) @ W2 + b2
// peh = relu(rel_pos @ pe_w1 + pe_b1)
// No __syncthreads: each wave stages and consumes its own LDS region.
// ---------------------------------------------------------------------------
__global__ __launch_bounds__(256, 2) void DensityAwareFeatureAggregator_main(
    const float* __restrict__ points,    // (B,N,3)
    const float* __restrict__ features,  // (B,N,32)
    const int*   __restrict__ nbr,       // (B,N,32)
    const float* __restrict__ pe_w1,     // (3,64)
    const float* __restrict__ pe_b1,     // (64)
    const float* __restrict__ mlp_w1,    // (96,128)  rows 0..31 = W1a
    const float* __restrict__ wc,        // (64,128)
    const float* __restrict__ b1c,       // (128)
    const float* __restrict__ w2,        // (128,64)
    const float* __restrict__ b2,        // (64)
    float* __restrict__ out)             // (B,N,64)
{
    __shared__ __align__(16) float s_f[4][KK][INF];   // 16 KB  gathered features
    __shared__ __align__(16) float s_pe[4][KK][PEF];  // 32 KB  pe hidden
    __shared__ __align__(16) float s_r[4][KK][4];     //  2 KB  rel_pos (padded)
    __shared__ int               s_i[4][KK];          // 0.5 KB neighbor idx

    const int t = threadIdx.x;
    const int w = t >> 6;   // wave in block = point slot
    const int l = t & 63;   // lane

    const int m = blockIdx.x * 4 + w;     // global point id, 0..B*N-1
    const int b = m >> 14;                // / N
    const int n = m & (NN - 1);           // % N

    const float* ptsB  = points   + (size_t)b * NN * 3;
    const float* featB = features + (size_t)b * NN * INF;
    const int*   nbrP  = nbr      + (size_t)m * KK;

    float (*sf)[INF]  = s_f[w];
    float (*spe)[PEF] = s_pe[w];
    float (*sr)[4]    = s_r[w];
    int*  si          = s_i[w];

    // ---- weight columns into registers (coalesced: consecutive lanes ->
    // consecutive addresses) ----
    float rw1a0[INF], rw1a1[INF];
#pragma unroll
    for (int c = 0; c < INF; ++c) {
        rw1a0[c] = mlp_w1[c * HID + l];
        rw1a1[c] = mlp_w1[c * HID + 64 + l];
    }
    float rwc0[PEF], rwc1[PEF];
#pragma unroll
    for (int c = 0; c < PEF; ++c) {
        rwc0[c] = wc[c * HID + l];
        rwc1[c] = wc[c * HID + 64 + l];
    }
    const float bc0 = b1c[l];
    const float bc1 = b1c[64 + l];

    // pe_w1 column for this lane (pe hidden j = l)
    const float pw0 = pe_w1[0 * PEF + l];
    const float pw1 = pe_w1[1 * PEF + l];
    const float pw2 = pe_w1[2 * PEF + l];
    const float pbv = pe_b1[l];

    // center coords (wave-uniform)
    const float cx = ptsB[n * 3 + 0];
    const float cy = ptsB[n * 3 + 1];
    const float cz = ptsB[n * 3 + 2];

    // ---- stage neighbor idx + rel_pos (lanes 0..31, one k each) ----
    if (l < KK) {
        int idx = nbrP[l];
        si[l]   = idx;
        sr[l][0] = ptsB[idx * 3 + 0] - cx;
        sr[l][1] = ptsB[idx * 3 + 1] - cy;
        sr[l][2] = ptsB[idx * 3 + 2] - cz;
    }

    // ---- stage gathered features: 32 k x 8 float4 = 256 float4, 4/lane ----
    const float4* featB4 = (const float4*)featB;
#pragma unroll
    for (int p = 0; p < 4; ++p) {
        int v  = p * 64 + l;
        int k  = v >> 3;
        int c4 = v & 7;
        int idx = si[k];
        ((float4*)&sf[k][0])[c4] = featB4[(size_t)idx * 8 + c4];
    }

    // ---- stage pe hidden: lane l computes pe column l for all 32 k ----
#pragma unroll 8
    for (int i = 0; i < KK; ++i) {
        float rx = sr[i][0], ry = sr[i][1], rz = sr[i][2];
        float v  = fmaf(rx, pw0, fmaf(ry, pw1, fmaf(rz, pw2, pbv)));
        spe[i][l] = fmaxf(v, 0.f);
    }

    // ---- main accumulation over K neighbors ----
    float acc0 = 0.f, acc1 = 0.f;
    for (int k = 0; k < KK; ++k) {
        const float4* f4 = (const float4*)&sf[k][0];
        const float4* p4 = (const float4*)&spe[k][0];
        // 4 partial chains for ILP
        float h0a = bc0, h0b = 0.f, h1a = bc1, h1b = 0.f;
#pragma unroll
        for (int c4 = 0; c4 < INF / 4; ++c4) {
            float4 f = f4[c4];
            int c = c4 * 4;
            h0a = fmaf(f.x, rw1a0[c + 0], h0a);
            h0b = fmaf(f.y, rw1a0[c + 1], h0b);
            h0a = fmaf(f.z, rw1a0[c + 2], h0a);
            h0b = fmaf(f.w, rw1a0[c + 3], h0b);
            h1a = fmaf(f.x, rw1a1[c + 0], h1a);
            h1b = fmaf(f.y, rw1a1[c + 1], h1b);
            h1a = fmaf(f.z, rw1a1[c + 2], h1a);
            h1b = fmaf(f.w, rw1a1[c + 3], h1b);
        }
#pragma unroll
        for (int c4 = 0; c4 < PEF / 4; ++c4) {
            float4 p = p4[c4];
            int c = c4 * 4;
            h0a = fmaf(p.x, rwc0[c + 0], h0a);
            h0b = fmaf(p.y, rwc0[c + 1], h0b);
            h0a = fmaf(p.z, rwc0[c + 2], h0a);
            h0b = fmaf(p.w, rwc0[c + 3], h0b);
            h1a = fmaf(p.x, rwc1[c + 0], h1a);
            h1b = fmaf(p.y, rwc1[c + 1], h1b);
            h1a = fmaf(p.z, rwc1[c + 2], h1a);
            h1b = fmaf(p.w, rwc1[c + 3], h1b);
        }
        acc0 += fmaxf(h0a + h0b, 0.f);
        acc1 += fmaxf(h1a + h1b, 0.f);
    }

    // ---- phase 2: out[m, l] = (mean h1) @ W2 + b2, via per-wave LDS hm ----
    float* hm = &sf[0][0];  // reuse own staging region (>=128 floats)
    hm[l]      = acc0 * (1.f / KK);
    hm[64 + l] = acc1 * (1.f / KK);
    // same-wave LDS write->read; compiler inserts lgkmcnt wait

    float o = b2[l];
#pragma unroll 8
    for (int j = 0; j < HID; ++j) {
        o = fmaf(hm[j], w2[j * OUTF + l], o);
    }
    out[(size_t)m * OUTF + l] = o;
}

// ---------------------------------------------------------------------------
extern "C" void kernel_launch(void* const* d_in, const int* in_sizes, int n_in,
                              void* d_out, int out_size, void* d_ws, size_t ws_size,
                              hipStream_t stream)
{
    const float* points   = (const float*)d_in[0];
    const float* features = (const float*)d_in[1];
    // d_in[2] density: provably unused (softmax over broadcast scalar = 1/K)
    const int*   nbr      = (const int*)d_in[3];
    const float* pe_w1    = (const float*)d_in[4];
    const float* pe_b1    = (const float*)d_in[5];
    const float* pe_w2    = (const float*)d_in[6];
    const float* pe_b2    = (const float*)d_in[7];
    const float* mlp_w1   = (const float*)d_in[8];
    const float* mlp_b1   = (const float*)d_in[9];
    const float* mlp_w2   = (const float*)d_in[10];
    const float* mlp_b2   = (const float*)d_in[11];

    float* wsf = (float*)d_ws;
    float* wc  = wsf;                 // 64*128 floats
    float* b1c = wsf + 64 * HID;      // 128 floats

    prep_kernel<<<1, 256, 0, stream>>>(pe_w2, pe_b2, mlp_w1, mlp_b1, wc, b1c);

    DensityAwareFeatureAggregator_main<<<(BB * NN) / 4, 256, 0, stream>>>(
        points, features, nbr, pe_w1, pe_b1, mlp_w1, wc, b1c, mlp_w2, mlp_b2,
        (float*)d_out);
}

// Round 2
// 497.232 us; speedup vs baseline: 1.7068x; 1.7068x over previous
//
#include <hip/hip_runtime.h>

#define BB   4
#define NN   16384
#define KK   32
#define HID  128
#define OUTF 64

typedef _Float16 f16x8 __attribute__((ext_vector_type(8)));
typedef float    f32x4 __attribute__((ext_vector_type(4)));

// ---------------------------------------------------------------------------
// prep1: wc = pe_w2 @ W1b (64x128), b1c = mlp_b1 + pe_b2 @ W1b
// (W1b = rows 32..95 of mlp_w1). Verified in round 1.
// ---------------------------------------------------------------------------
__global__ __launch_bounds__(256) void prep1_kernel(
    const float* __restrict__ pe_w2, const float* __restrict__ pe_b2,
    const float* __restrict__ mlp_w1, const float* __restrict__ mlp_b1,
    float* __restrict__ wc, float* __restrict__ b1c)
{
    __shared__ float s_w2[64 * 64];
    __shared__ float s_b2[64];
    int t = threadIdx.x;
    for (int i = t; i < 64 * 64; i += 256) s_w2[i] = pe_w2[i];
    if (t < 64) s_b2[t] = pe_b2[t];
    __syncthreads();

    int j = t & 127, half = t >> 7;
    float col[64];
#pragma unroll
    for (int c = 0; c < 64; ++c) col[c] = mlp_w1[(32 + c) * HID + j];

    if (half == 0) {
        float bacc = mlp_b1[j];
#pragma unroll 16
        for (int c = 0; c < 64; ++c) bacc = fmaf(s_b2[c], col[c], bacc);
        b1c[j] = bacc;
    }
    for (int i = half * 32; i < half * 32 + 32; ++i) {
        float a = 0.f;
#pragma unroll 16
        for (int c = 0; c < 64; ++c) a = fmaf(s_w2[i * 64 + c], col[c], a);
        wc[i * HID + j] = a;
    }
}

// ---------------------------------------------------------------------------
// prep2: pack fp16 B-fragments.
// W1c (96x128): rows 0..31 = mlp_w1 rows 0..31, rows 32..95 = wc.
//   24 tiles (ks 0..2, nt 0..7): gB1[tile*512 + l*8 + j] =
//     W1c[ks*32 + (l>>4)*8 + j][nt*16 + (l&15)]
// W2 (128x64): 16 tiles (ks 0..3, nt 0..3) same packing into gW2.
// ---------------------------------------------------------------------------
__global__ __launch_bounds__(256) void prep2_kernel(
    const float* __restrict__ mlp_w1, const float* __restrict__ wc,
    const float* __restrict__ mlp_w2,
    _Float16* __restrict__ gB1, _Float16* __restrict__ gW2)
{
    int t = blockIdx.x * 256 + threadIdx.x;
    if (t < 24 * 512) {
        int tile = t >> 9, rem = t & 511, l = rem >> 3, j = rem & 7;
        int ks = tile >> 3, nt = tile & 7, q = l >> 4;
        int k = ks * 32 + q * 8 + j, n = nt * 16 + (l & 15);
        float v = (k < 32) ? mlp_w1[k * HID + n] : wc[(k - 32) * HID + n];
        gB1[t] = (_Float16)v;
    } else {
        int t2 = t - 24 * 512;
        int tile = t2 >> 9, rem = t2 & 511, l = rem >> 3, j = rem & 7;
        int ks = tile >> 2, nt = tile & 3, q = l >> 4;
        int k = ks * 32 + q * 8 + j, n = nt * 16 + (l & 15);
        gW2[t2] = (_Float16)mlp_w2[k * OUTF + n];
    }
}

// ---------------------------------------------------------------------------
// Main: one wave per point, mfma_f32_16x16x32_f16.
// Per point: D(32x128) = X(32x96) @ W1c + b1c; relu; mean rows -> hm(128);
// every 16 points: OUT(16x64) = HM(16x128) @ W2 + b2 via 16 MFMAs.
// ---------------------------------------------------------------------------
__global__ __launch_bounds__(256, 2) void DensityAwareFeatureAggregator_main(
    const float* __restrict__ points,    // (B,N,3)
    const float* __restrict__ features,  // (B,N,32)
    const int*   __restrict__ nbr,       // (B,N,32)
    const float* __restrict__ pe_w1,     // (3,64)
    const float* __restrict__ pe_b1,     // (64)
    const float* __restrict__ b1c,       // (128) fused bias
    const _Float16* __restrict__ gB1,    // W1c frags
    const _Float16* __restrict__ gW2,    // W2 frags
    const float* __restrict__ b2g,       // (64)
    float* __restrict__ out)             // (B,N,64)
{
    __shared__ __align__(16) _Float16 sB1[24 * 512];     // 24576 B
    __shared__ __align__(16) _Float16 sW2[16 * 512];     // 16384 B
    __shared__ __align__(16) float    sR[4][32][4];      //  2048 B
    __shared__ int                    sI[4][32];         //   512 B
    __shared__ __align__(16) _Float16 sHM[4][16 * 136];  // 17408 B  (pad 136)

    const int t = threadIdx.x;
    // cooperative LDS fill of weight fragments (once per block)
    {
        const uint4* sB = (const uint4*)gB1;
        uint4* dB = (uint4*)sB1;
        for (int i = t; i < 1536; i += 256) dB[i] = sB[i];
        const uint4* sW = (const uint4*)gW2;
        uint4* dW = (uint4*)sW2;
        for (int i = t; i < 1024; i += 256) dW[i] = sW[i];
    }
    __syncthreads();

    const int w = t >> 6, l = t & 63, q = l >> 4, c16 = l & 15;

    // pe_w1 columns this lane needs: ks1 -> cols q*8+j, ks2 -> cols 32+q*8+j
    float pwx[16], pwy[16], pwz[16], pbb[16];
#pragma unroll
    for (int s = 0; s < 16; ++s) {
        int c = (s < 8) ? (q * 8 + s) : (32 + q * 8 + (s - 8));
        pwx[s] = pe_w1[c];
        pwy[s] = pe_w1[64 + c];
        pwz[s] = pe_w1[128 + c];
        pbb[s] = pe_b1[c];
    }
    float bias1[8];
#pragma unroll
    for (int nt = 0; nt < 8; ++nt) bias1[nt] = b1c[nt * 16 + c16];
    float bias2[4];
#pragma unroll
    for (int nt = 0; nt < 4; ++nt) bias2[nt] = b2g[nt * 16 + c16];

    const f16x8* B1f = (const f16x8*)sB1;
    const f16x8* W2f = (const f16x8*)sW2;

    const int waveId = blockIdx.x * 4 + w;
    const int nWaves = gridDim.x * 4;
    const int nSG = (BB * NN) / 16;

#pragma unroll 1
    for (int sg = waveId; sg < nSG; sg += nWaves) {
        const int base = sg * 16;
#pragma unroll 1
        for (int p = 0; p < 16; ++p) {
            const int m = base + p;
            const int b = m >> 14;
            const int n = m & (NN - 1);
            const float*  ptsB = points + (size_t)b * NN * 3;
            const float4* fB   = (const float4*)(features + (size_t)b * NN * 32);

            // stage neighbor idx + rel_pos (lanes 0..31)
            if (l < KK) {
                int idx = nbr[(size_t)m * KK + l];
                sI[w][l] = idx;
                float cx = ptsB[n * 3 + 0], cy = ptsB[n * 3 + 1], cz = ptsB[n * 3 + 2];
                sR[w][l][0] = ptsB[idx * 3 + 0] - cx;
                sR[w][l][1] = ptsB[idx * 3 + 1] - cy;
                sR[w][l][2] = ptsB[idx * 3 + 2] - cz;
            }

            // A-frags for features K-step: lane reads feats[idx][q*8..q*8+7]
            int i0 = sI[w][c16];
            int i1 = sI[w][16 + c16];
            float4 f0a = fB[(size_t)i0 * 8 + q * 2];
            float4 f0b = fB[(size_t)i0 * 8 + q * 2 + 1];
            float4 f1a = fB[(size_t)i1 * 8 + q * 2];
            float4 f1b = fB[(size_t)i1 * 8 + q * 2 + 1];
            f16x8 af0, af1;
            af0[0] = (_Float16)f0a.x; af0[1] = (_Float16)f0a.y;
            af0[2] = (_Float16)f0a.z; af0[3] = (_Float16)f0a.w;
            af0[4] = (_Float16)f0b.x; af0[5] = (_Float16)f0b.y;
            af0[6] = (_Float16)f0b.z; af0[7] = (_Float16)f0b.w;
            af1[0] = (_Float16)f1a.x; af1[1] = (_Float16)f1a.y;
            af1[2] = (_Float16)f1a.z; af1[3] = (_Float16)f1a.w;
            af1[4] = (_Float16)f1b.x; af1[5] = (_Float16)f1b.y;
            af1[6] = (_Float16)f1b.z; af1[7] = (_Float16)f1b.w;

            // peh A-frags computed in-lane
            const float4* sr4 = (const float4*)&sR[w][0][0];
            float4 r0 = sr4[c16];
            float4 r1 = sr4[16 + c16];
            f16x8 ap10, ap20, ap11, ap21;
#pragma unroll
            for (int j = 0; j < 8; ++j) {
                float v;
                v = fmaf(r0.x, pwx[j],     fmaf(r0.y, pwy[j],     fmaf(r0.z, pwz[j],     pbb[j])));
                ap10[j] = (_Float16)fmaxf(v, 0.f);
                v = fmaf(r0.x, pwx[8 + j], fmaf(r0.y, pwy[8 + j], fmaf(r0.z, pwz[8 + j], pbb[8 + j])));
                ap20[j] = (_Float16)fmaxf(v, 0.f);
                v = fmaf(r1.x, pwx[j],     fmaf(r1.y, pwy[j],     fmaf(r1.z, pwz[j],     pbb[j])));
                ap11[j] = (_Float16)fmaxf(v, 0.f);
                v = fmaf(r1.x, pwx[8 + j], fmaf(r1.y, pwy[8 + j], fmaf(r1.z, pwz[8 + j], pbb[8 + j])));
                ap21[j] = (_Float16)fmaxf(v, 0.f);
            }

            // MFMA main: 3 K-steps x 8 N-tiles x 2 M-tiles
            f32x4 acc[2][8];
#pragma unroll
            for (int nt = 0; nt < 8; ++nt) {
                f32x4 z; z[0] = z[1] = z[2] = z[3] = bias1[nt];
                acc[0][nt] = z; acc[1][nt] = z;
            }
#pragma unroll
            for (int nt = 0; nt < 8; ++nt) {
                f16x8 bf = B1f[nt * 64 + l];
                acc[0][nt] = __builtin_amdgcn_mfma_f32_16x16x32_f16(af0, bf, acc[0][nt], 0, 0, 0);
                acc[1][nt] = __builtin_amdgcn_mfma_f32_16x16x32_f16(af1, bf, acc[1][nt], 0, 0, 0);
            }
#pragma unroll
            for (int nt = 0; nt < 8; ++nt) {
                f16x8 bf = B1f[(8 + nt) * 64 + l];
                acc[0][nt] = __builtin_amdgcn_mfma_f32_16x16x32_f16(ap10, bf, acc[0][nt], 0, 0, 0);
                acc[1][nt] = __builtin_amdgcn_mfma_f32_16x16x32_f16(ap11, bf, acc[1][nt], 0, 0, 0);
            }
#pragma unroll
            for (int nt = 0; nt < 8; ++nt) {
                f16x8 bf = B1f[(16 + nt) * 64 + l];
                acc[0][nt] = __builtin_amdgcn_mfma_f32_16x16x32_f16(ap20, bf, acc[0][nt], 0, 0, 0);
                acc[1][nt] = __builtin_amdgcn_mfma_f32_16x16x32_f16(ap21, bf, acc[1][nt], 0, 0, 0);
            }

            // relu + mean over 32 rows -> hm row p (fp16, A-frag friendly)
#pragma unroll
            for (int nt = 0; nt < 8; ++nt) {
                float s = fmaxf(acc[0][nt][0], 0.f) + fmaxf(acc[0][nt][1], 0.f)
                        + fmaxf(acc[0][nt][2], 0.f) + fmaxf(acc[0][nt][3], 0.f)
                        + fmaxf(acc[1][nt][0], 0.f) + fmaxf(acc[1][nt][1], 0.f)
                        + fmaxf(acc[1][nt][2], 0.f) + fmaxf(acc[1][nt][3], 0.f);
                s += __shfl_xor(s, 16, 64);
                s += __shfl_xor(s, 32, 64);
                if (q == 0) sHM[w][p * 136 + nt * 16 + c16] = (_Float16)(s * 0.03125f);
            }
        }

        // epilogue: OUT(16x64) = HM(16x128) @ W2 + b2
        f32x4 acc2[4];
#pragma unroll
        for (int nt = 0; nt < 4; ++nt) {
            f32x4 z; z[0] = z[1] = z[2] = z[3] = bias2[nt];
            acc2[nt] = z;
        }
#pragma unroll
        for (int ks = 0; ks < 4; ++ks) {
            f16x8 a2 = *(const f16x8*)&sHM[w][c16 * 136 + ks * 32 + q * 8];
#pragma unroll
            for (int nt = 0; nt < 4; ++nt) {
                f16x8 bf = W2f[(ks * 4 + nt) * 64 + l];
                acc2[nt] = __builtin_amdgcn_mfma_f32_16x16x32_f16(a2, bf, acc2[nt], 0, 0, 0);
            }
        }
#pragma unroll
        for (int nt = 0; nt < 4; ++nt)
#pragma unroll
            for (int r = 0; r < 4; ++r)
                out[(size_t)(base + q * 4 + r) * OUTF + nt * 16 + c16] = acc2[nt][r];
    }
}

// ---------------------------------------------------------------------------
extern "C" void kernel_launch(void* const* d_in, const int* in_sizes, int n_in,
                              void* d_out, int out_size, void* d_ws, size_t ws_size,
                              hipStream_t stream)
{
    const float* points   = (const float*)d_in[0];
    const float* features = (const float*)d_in[1];
    // d_in[2] density: provably unused (softmax over K identical values = 1/K)
    const int*   nbr      = (const int*)d_in[3];
    const float* pe_w1    = (const float*)d_in[4];
    const float* pe_b1    = (const float*)d_in[5];
    const float* pe_w2    = (const float*)d_in[6];
    const float* pe_b2    = (const float*)d_in[7];
    const float* mlp_w1   = (const float*)d_in[8];
    const float* mlp_b1   = (const float*)d_in[9];
    const float* mlp_w2   = (const float*)d_in[10];
    const float* mlp_b2   = (const float*)d_in[11];

    float* wsf = (float*)d_ws;
    float* wc  = wsf;                                   // 64*128 f32
    float* b1c = wsf + 64 * HID;                        // 128 f32
    _Float16* gB1 = (_Float16*)(wsf + 64 * HID + 128);  // 12288 f16
    _Float16* gW2 = gB1 + 24 * 512;                     // 8192 f16

    prep1_kernel<<<1, 256, 0, stream>>>(pe_w2, pe_b2, mlp_w1, mlp_b1, wc, b1c);
    prep2_kernel<<<80, 256, 0, stream>>>(mlp_w1, wc, mlp_w2, gB1, gW2);

    DensityAwareFeatureAggregator_main<<<512, 256, 0, stream>>>(
        points, features, nbr, pe_w1, pe_b1, b1c, gB1, gW2, mlp_b2,
        (float*)d_out);
}